// Round 7
// baseline (310.874 us; speedup 1.0000x reference)
//
#include <hip/hip_runtime.h>

#define BN 262144
#define LNUM 15
// slab: 151 stages x 72 floats; stage lin = l*10 + net*5 + st; stage 150 = copy of stage 0
#define NSTG 151

extern "C" __global__ void build_slab(
    const float* __restrict__ Wi, const float* __restrict__ bi,
    const float* __restrict__ Wh, const float* __restrict__ bh,
    const float* __restrict__ Wo, const float* __restrict__ bo,
    float* __restrict__ slab) {
    int idx = blockIdx.x * 256 + threadIdx.x;
    if (idx >= NSTG * 72) return;
    int sl = idx / 72, k = idx % 72;
    if (sl == NSTG - 1) sl = 0;                 // duplicate stage for tail prefetch
    const int l = sl / 10, r = sl % 10, net = r / 5, st = r % 5;
    const int nb = l * 2 + net;
    float v;
    if (k < 64) {
        if (st == 0)      v = Wi[nb * 64 + k];
        else if (st < 4)  v = Wh[(nb * 3 + (st - 1)) * 64 + k];
        else              v = Wo[nb * 64 + k];
    } else {
        const int o = k - 64;
        if (st == 0)      v = bi[nb * 8 + o];
        else if (st < 4)  v = bh[(nb * 3 + (st - 1)) * 8 + o];
        else              v = bo[nb * 8 + o];
    }
    slab[idx] = v;
}

// access float j of an 18-float4 VGPR buffer with compile-time j
#define WB(buf, k) ((k) % 4 == 0 ? buf[(k) / 4].x : (k) % 4 == 1 ? buf[(k) / 4].y \
                  : (k) % 4 == 2 ? buf[(k) / 4].z : buf[(k) / 4].w)

// issue 18 broadcast global_load_dwordx4 for the stage at float-offset foff.
// zoff is an opaque VGPR 0: defeats uniformity analysis so these STAY on the
// VMEM pipe (r6's uniform loads were scalarized back to serialized s_load).
#define PREF(dst, foff)                                                          \
    {                                                                            \
        const float4* sp = reinterpret_cast<const float4*>(Wl + (foff) + zoff);  \
        _Pragma("unroll") for (int j = 0; j < 18; ++j) dst[j] = sp[j];           \
    }

__device__ __forceinline__ void mv8(const float in[8], const float4 buf[18], float out[8]) {
#pragma unroll
    for (int o = 0; o < 8; ++o) out[o] = fmaf(in[0], WB(buf, o), WB(buf, 64 + o));
#pragma unroll
    for (int i = 1; i < 8; ++i)
#pragma unroll
        for (int o = 0; o < 8; ++o) out[o] = fmaf(in[i], WB(buf, i * 8 + o), out[o]);
}

__device__ __forceinline__ void lr8(float v[8]) {
#pragma unroll
    for (int o = 0; o < 8; ++o) v[o] = fmaxf(v[o], 0.01f * v[o]);
}

// 1 thread = 1 sample; weights VMEM-broadcast into ping-pong VGPR buffers,
// prefetched one stage ahead; compiler's counted vmcnt pipelines load vs FMA.
extern "C" __global__ void __launch_bounds__(256) flow_fwd(
    const float* __restrict__ z, const float* __restrict__ slab,
    const int* __restrict__ perms,
    float* __restrict__ outy, float* __restrict__ outld) {
    __shared__ float xs[256 * 17];   // private permute slot, stride 17 (odd)
    const int t = threadIdx.x;
    const long i = (long)blockIdx.x * 256 + t;
    float* __restrict__ myx = &xs[t * 17];

    int zoff;
    asm("v_mov_b32 %0, 0" : "=v"(zoff));   // opaque 0 in a VGPR

    float4 A[18], Bq[18];
    {
        const float* __restrict__ Wl = slab;
        PREF(A, 0)                    // stage (0,0,0)
    }
    float x[16];
    {
        const float4* zp = reinterpret_cast<const float4*>(z + i * 16);
        float4 a0 = zp[0], a1 = zp[1], a2 = zp[2], a3 = zp[3];
        x[0] = a0.x;  x[1] = a0.y;  x[2] = a0.z;  x[3] = a0.w;
        x[4] = a1.x;  x[5] = a1.y;  x[6] = a1.z;  x[7] = a1.w;
        x[8] = a2.x;  x[9] = a2.y;  x[10] = a2.z; x[11] = a2.w;
        x[12] = a3.x; x[13] = a3.y; x[14] = a3.z; x[15] = a3.w;
    }
    float ld = 0.f;

#pragma unroll 1
    for (int l = 0; l < LNUM; ++l) {
        const float* __restrict__ Wl = slab + l * 720;
        float h[8], g[8], sf[8], bf[8];
        // net 0 (log_s):  A, B, A, B, A   | net 1 (b): B, A, B, A, B
        PREF(Bq, 72)  mv8(x, A, h);  lr8(h);
        PREF(A, 144)  mv8(h, Bq, g); lr8(g);
        PREF(Bq, 216) mv8(g, A, h);  lr8(h);
        PREF(A, 288)  mv8(h, Bq, g); lr8(g);
        PREF(Bq, 360) mv8(g, A, sf);
        PREF(A, 432)  mv8(x, Bq, h); lr8(h);
        PREF(Bq, 504) mv8(h, A, g);  lr8(g);
        PREF(A, 576)  mv8(g, Bq, h); lr8(h);
        PREF(Bq, 648) mv8(h, A, g);  lr8(g);
        PREF(A, 720)  mv8(g, Bq, bf);        // also preloads next layer's stage 0

#pragma unroll
        for (int k = 0; k < 8; ++k) {
            const float cs = fminf(fmaxf(sf[k], -5.f), 5.f);
            ld += cs;
            x[8 + k] = fmaf(__expf(cs) + 1e-6f, x[8 + k], bf[k]);
        }
        // register permutation via private LDS slot (runtime uniform indices)
#pragma unroll
        for (int p = 0; p < 16; ++p) myx[p] = x[p];
        const int* pl = perms + l * 16;
#pragma unroll
        for (int j = 0; j < 16; ++j) x[j] = myx[pl[j]];
    }

    float* yrow = outy + i * 16;
    float4 o0, o1, o2, o3;
    o0.x = x[0];  o0.y = x[1];  o0.z = x[2];  o0.w = x[3];
    o1.x = x[4];  o1.y = x[5];  o1.z = x[6];  o1.w = x[7];
    o2.x = x[8];  o2.y = x[9];  o2.z = x[10]; o2.w = x[11];
    o3.x = x[12]; o3.y = x[13]; o3.z = x[14]; o3.w = x[15];
    reinterpret_cast<float4*>(yrow)[0] = o0;
    reinterpret_cast<float4*>(yrow)[1] = o1;
    reinterpret_cast<float4*>(yrow)[2] = o2;
    reinterpret_cast<float4*>(yrow)[3] = o3;
    outld[i] = ld;
}

extern "C" void kernel_launch(void* const* d_in, const int* in_sizes, int n_in,
                              void* d_out, int out_size, void* d_ws, size_t ws_size,
                              hipStream_t stream) {
    const float* z = (const float*)d_in[0];
    const float* Wi = (const float*)d_in[1];
    const float* bi = (const float*)d_in[2];
    const float* Wh = (const float*)d_in[3];
    const float* bh = (const float*)d_in[4];
    const float* Wo = (const float*)d_in[5];
    const float* bo = (const float*)d_in[6];
    const int* perms = (const int*)d_in[7];
    float* out = (float*)d_out;
    float* slab = (float*)d_ws;   // 151*72 floats = 43.5 KB

    hipLaunchKernelGGL(build_slab, dim3((NSTG * 72 + 255) / 256), dim3(256), 0, stream,
                       Wi, bi, Wh, bh, Wo, bo, slab);
    hipLaunchKernelGGL(flow_fwd, dim3(BN / 256), dim3(256), 0, stream,
                       z, slab, perms, out, out + (size_t)BN * 16);
}

// Round 8
// 125.829 us; speedup vs baseline: 2.4706x; 2.4706x over previous
//
#include <hip/hip_runtime.h>

#define BN 262144
#define HALF (BN / 2)
#define LNUM 15
// slab: 151 stages x 72 floats; stage lin = l*10 + net*5 + st (stage 150 unused pad)
#define NSTG 151

extern "C" __global__ void build_slab(
    const float* __restrict__ Wi, const float* __restrict__ bi,
    const float* __restrict__ Wh, const float* __restrict__ bh,
    const float* __restrict__ Wo, const float* __restrict__ bo,
    float* __restrict__ slab) {
    int idx = blockIdx.x * 256 + threadIdx.x;
    if (idx >= NSTG * 72) return;
    int sl = idx / 72, k = idx % 72;
    if (sl == NSTG - 1) sl = 0;
    const int l = sl / 10, r = sl % 10, net = r / 5, st = r % 5;
    const int nb = l * 2 + net;
    float v;
    if (k < 64) {
        if (st == 0)      v = Wi[nb * 64 + k];
        else if (st < 4)  v = Wh[(nb * 3 + (st - 1)) * 64 + k];
        else              v = Wo[nb * 64 + k];
    } else {
        const int o = k - 64;
        if (st == 0)      v = bi[nb * 8 + o];
        else if (st < 4)  v = bh[(nb * 3 + (st - 1)) * 8 + o];
        else              v = bo[nb * 8 + o];
    }
    slab[idx] = v;
}

// dual-sample matvec: weights are block-uniform -> s_load; each v_fmac reads
// the weight as its one-allowed SGPR operand (broadcast, no per-lane copies).
__device__ __forceinline__ void mv8x2(const float a[8], const float b[8],
                                      const float* __restrict__ W,
                                      float oa[8], float ob[8]) {
#pragma unroll
    for (int o = 0; o < 8; ++o) {
        const float w0 = W[o], bb = W[64 + o];
        oa[o] = fmaf(a[0], w0, bb);
        ob[o] = fmaf(b[0], w0, bb);
    }
#pragma unroll
    for (int i = 1; i < 8; ++i)
#pragma unroll
        for (int o = 0; o < 8; ++o) {
            const float w = W[i * 8 + o];
            oa[o] = fmaf(a[i], w, oa[o]);
            ob[o] = fmaf(b[i], w, ob[o]);
        }
}

__device__ __forceinline__ void lr8(float v[8]) {
#pragma unroll
    for (int o = 0; o < 8; ++o) v[o] = fmaxf(v[o], 0.01f * v[o]);
}

// 1 thread = 2 samples (i and i+HALF). Scalar-pipe weights amortized over
// 2x FMA work; dual independent chains give in-wave ILP at 2 waves/SIMD.
extern "C" __global__ void __launch_bounds__(256) flow_fwd(
    const float* __restrict__ z, const float* __restrict__ slab,
    const int* __restrict__ perms,
    float* __restrict__ outy, float* __restrict__ outld) {
    __shared__ float xs[256 * 34];  // two private stride-17 permute slots/thread
    const int t = threadIdx.x;
    const long i = (long)blockIdx.x * 256 + t;
    float* __restrict__ mA = &xs[t * 34];
    float* __restrict__ mB = mA + 17;

    float xA[16], xB[16];
    {
        const float4* zp = reinterpret_cast<const float4*>(z + i * 16);
#pragma unroll
        for (int q = 0; q < 4; ++q) {
            float4 a = zp[q];
            xA[4 * q] = a.x; xA[4 * q + 1] = a.y; xA[4 * q + 2] = a.z; xA[4 * q + 3] = a.w;
        }
        const float4* zq = reinterpret_cast<const float4*>(z + (i + HALF) * 16);
#pragma unroll
        for (int q = 0; q < 4; ++q) {
            float4 a = zq[q];
            xB[4 * q] = a.x; xB[4 * q + 1] = a.y; xB[4 * q + 2] = a.z; xB[4 * q + 3] = a.w;
        }
    }
    float ldA = 0.f, ldB = 0.f;

#pragma unroll 1
    for (int l = 0; l < LNUM; ++l) {
        const float* __restrict__ Wl = slab + l * 720;
        float hA[8], hB[8], gA[8], gB[8], sA[8], sB[8], bA[8], bB[8];
        // net 0: log_s
        mv8x2(xA, xB, Wl + 0,   hA, hB); lr8(hA); lr8(hB);
        mv8x2(hA, hB, Wl + 72,  gA, gB); lr8(gA); lr8(gB);
        mv8x2(gA, gB, Wl + 144, hA, hB); lr8(hA); lr8(hB);
        mv8x2(hA, hB, Wl + 216, gA, gB); lr8(gA); lr8(gB);
        mv8x2(gA, gB, Wl + 288, sA, sB);
        // net 1: b
        mv8x2(xA, xB, Wl + 360, hA, hB); lr8(hA); lr8(hB);
        mv8x2(hA, hB, Wl + 432, gA, gB); lr8(gA); lr8(gB);
        mv8x2(gA, gB, Wl + 504, hA, hB); lr8(hA); lr8(hB);
        mv8x2(hA, hB, Wl + 576, gA, gB); lr8(gA); lr8(gB);
        mv8x2(gA, gB, Wl + 648, bA, bB);

#pragma unroll
        for (int k = 0; k < 8; ++k) {
            const float cA = fminf(fmaxf(sA[k], -5.f), 5.f);
            const float cB = fminf(fmaxf(sB[k], -5.f), 5.f);
            ldA += cA; ldB += cB;
            xA[8 + k] = fmaf(__expf(cA) + 1e-6f, xA[8 + k], bA[k]);
            xB[8 + k] = fmaf(__expf(cB) + 1e-6f, xB[8 + k], bB[k]);
        }
        // register permutation via private LDS slots (uniform runtime indices)
#pragma unroll
        for (int p = 0; p < 16; ++p) { mA[p] = xA[p]; mB[p] = xB[p]; }
        const int* __restrict__ pl = perms + l * 16;
#pragma unroll
        for (int j = 0; j < 16; ++j) { xA[j] = mA[pl[j]]; xB[j] = mB[pl[j]]; }
    }

    {
        float4* ya = reinterpret_cast<float4*>(outy + i * 16);
#pragma unroll
        for (int q = 0; q < 4; ++q) {
            float4 a;
            a.x = xA[4 * q]; a.y = xA[4 * q + 1]; a.z = xA[4 * q + 2]; a.w = xA[4 * q + 3];
            ya[q] = a;
        }
        float4* yb = reinterpret_cast<float4*>(outy + (i + HALF) * 16);
#pragma unroll
        for (int q = 0; q < 4; ++q) {
            float4 a;
            a.x = xB[4 * q]; a.y = xB[4 * q + 1]; a.z = xB[4 * q + 2]; a.w = xB[4 * q + 3];
            yb[q] = a;
        }
    }
    outld[i] = ldA;
    outld[i + HALF] = ldB;
}

extern "C" void kernel_launch(void* const* d_in, const int* in_sizes, int n_in,
                              void* d_out, int out_size, void* d_ws, size_t ws_size,
                              hipStream_t stream) {
    const float* z = (const float*)d_in[0];
    const float* Wi = (const float*)d_in[1];
    const float* bi = (const float*)d_in[2];
    const float* Wh = (const float*)d_in[3];
    const float* bh = (const float*)d_in[4];
    const float* Wo = (const float*)d_in[5];
    const float* bo = (const float*)d_in[6];
    const int* perms = (const int*)d_in[7];
    float* out = (float*)d_out;
    float* slab = (float*)d_ws;   // 151*72 floats

    hipLaunchKernelGGL(build_slab, dim3((NSTG * 72 + 255) / 256), dim3(256), 0, stream,
                       Wi, bi, Wh, bh, Wo, bo, slab);
    hipLaunchKernelGGL(flow_fwd, dim3(HALF / 256), dim3(256), 0, stream,
                       z, slab, perms, out, out + (size_t)BN * 16);
}

// Round 9
// 99.256 us; speedup vs baseline: 3.1320x; 1.2677x over previous
//
#include <hip/hip_runtime.h>

#define BN 262144
#define HALF (BN / 2)
#define LNUM 15
// slab: 151 stages x 72 floats; stage lin = l*10 + net*5 + st; stage 150 = dup of stage 0
#define NSTG 151
#define NF4 (NSTG * 18)   // 2718 float4

extern "C" __global__ void build_slab(
    const float* __restrict__ Wi, const float* __restrict__ bi,
    const float* __restrict__ Wh, const float* __restrict__ bh,
    const float* __restrict__ Wo, const float* __restrict__ bo,
    float* __restrict__ slab) {
    int idx = blockIdx.x * 256 + threadIdx.x;
    if (idx >= NSTG * 72) return;
    int sl = idx / 72, k = idx % 72;
    if (sl == NSTG - 1) sl = 0;
    const int l = sl / 10, r = sl % 10, net = r / 5, st = r % 5;
    const int nb = l * 2 + net;
    float v;
    if (k < 64) {
        if (st == 0)      v = Wi[nb * 64 + k];
        else if (st < 4)  v = Wh[(nb * 3 + (st - 1)) * 64 + k];
        else              v = Wo[nb * 64 + k];
    } else {
        const int o = k - 64;
        if (st == 0)      v = bi[nb * 8 + o];
        else if (st < 4)  v = bh[(nb * 3 + (st - 1)) * 8 + o];
        else              v = bo[nb * 8 + o];
    }
    slab[idx] = v;
}

// access float k of an 18-float4 register buffer with compile-time k
#define WB(buf, k) ((k) % 4 == 0 ? buf[(k) / 4].x : (k) % 4 == 1 ? buf[(k) / 4].y \
                  : (k) % 4 == 2 ? buf[(k) / 4].z : buf[(k) / 4].w)

// stage sidx: 18 broadcast ds_read_b128 from the LDS slab into a VGPR buffer.
// Same-address-across-lanes = HW broadcast: no conflicts, no per-lane return
// amplification, and (unlike r6) CANNOT be demoted to serialized s_load.
#define PREFL(dst, sidx)                                                     \
    {                                                                        \
        const float4* sp = &wls[(sidx) * 18];                                \
        _Pragma("unroll") for (int j = 0; j < 18; ++j) dst[j] = sp[j];       \
    }

// dual-sample matvec: 128 FMAs, weights from VGPR buffer (all-VGPR v_fmac)
__device__ __forceinline__ void mv8x2(const float a[8], const float b[8],
                                      const float4 buf[18],
                                      float oa[8], float ob[8]) {
#pragma unroll
    for (int o = 0; o < 8; ++o) {
        const float w0 = WB(buf, o), bb = WB(buf, 64 + o);
        oa[o] = fmaf(a[0], w0, bb);
        ob[o] = fmaf(b[0], w0, bb);
    }
#pragma unroll
    for (int i = 1; i < 8; ++i)
#pragma unroll
        for (int o = 0; o < 8; ++o) {
            const float w = WB(buf, i * 8 + o);
            oa[o] = fmaf(a[i], w, oa[o]);
            ob[o] = fmaf(b[i], w, ob[o]);
        }
}

__device__ __forceinline__ void lr8(float v[8]) {
#pragma unroll
    for (int o = 0; o < 8; ++o) v[o] = fmaxf(v[o], 0.01f * v[o]);
}

// 1 thread = 2 samples; weights LDS-resident, broadcast-read into ping-pong
// VGPR stage buffers one stage ahead (vmem/scalar pipes fully off the loop).
extern "C" __global__ void __launch_bounds__(512, 2) flow_fwd(
    const float* __restrict__ z, const float* __restrict__ slab,
    const int* __restrict__ perms,
    float* __restrict__ outy, float* __restrict__ outld) {
    __shared__ float4 wls[NF4];      // 43.5 KB weight slab
    __shared__ float xs[512 * 35];   // two private stride-17 permute slots, 35=odd
    const int t = threadIdx.x;
    const long i = (long)blockIdx.x * 512 + t;
    float* __restrict__ mA = &xs[t * 35];
    float* __restrict__ mB = mA + 17;

    // block-cooperative slab copy (one-time)
    {
        const float4* gs = reinterpret_cast<const float4*>(slab);
        for (int k = t; k < NF4; k += 512) wls[k] = gs[k];
    }

    float xA[16], xB[16];
    {
        const float4* zp = reinterpret_cast<const float4*>(z + i * 16);
#pragma unroll
        for (int q = 0; q < 4; ++q) {
            float4 a = zp[q];
            xA[4 * q] = a.x; xA[4 * q + 1] = a.y; xA[4 * q + 2] = a.z; xA[4 * q + 3] = a.w;
        }
        const float4* zq = reinterpret_cast<const float4*>(z + (i + HALF) * 16);
#pragma unroll
        for (int q = 0; q < 4; ++q) {
            float4 a = zq[q];
            xB[4 * q] = a.x; xB[4 * q + 1] = a.y; xB[4 * q + 2] = a.z; xB[4 * q + 3] = a.w;
        }
    }
    float ldA = 0.f, ldB = 0.f;
    __syncthreads();

    float4 A[18], Bq[18];
    PREFL(A, 0)

#pragma unroll 1
    for (int l = 0; l < LNUM; ++l) {
        const int base = l * 10;
        float hA[8], hB[8], gA[8], gB[8], sA[8], sB[8], bA[8], bB[8];
        // net 0 (log_s): stages base+0..4 ; net 1 (b): base+5..9
        PREFL(Bq, base + 1)  mv8x2(xA, xB, A,  hA, hB); lr8(hA); lr8(hB);
        PREFL(A,  base + 2)  mv8x2(hA, hB, Bq, gA, gB); lr8(gA); lr8(gB);
        PREFL(Bq, base + 3)  mv8x2(gA, gB, A,  hA, hB); lr8(hA); lr8(hB);
        PREFL(A,  base + 4)  mv8x2(hA, hB, Bq, gA, gB); lr8(gA); lr8(gB);
        PREFL(Bq, base + 5)  mv8x2(gA, gB, A,  sA, sB);
        PREFL(A,  base + 6)  mv8x2(xA, xB, Bq, hA, hB); lr8(hA); lr8(hB);
        PREFL(Bq, base + 7)  mv8x2(hA, hB, A,  gA, gB); lr8(gA); lr8(gB);
        PREFL(A,  base + 8)  mv8x2(gA, gB, Bq, hA, hB); lr8(hA); lr8(hB);
        PREFL(Bq, base + 9)  mv8x2(hA, hB, A,  gA, gB); lr8(gA); lr8(gB);
        PREFL(A,  base + 10) mv8x2(gA, gB, Bq, bA, bB);   // also next layer's stage 0

#pragma unroll
        for (int k = 0; k < 8; ++k) {
            const float cA = fminf(fmaxf(sA[k], -5.f), 5.f);
            const float cB = fminf(fmaxf(sB[k], -5.f), 5.f);
            ldA += cA; ldB += cB;
            xA[8 + k] = fmaf(__expf(cA) + 1e-6f, xA[8 + k], bA[k]);
            xB[8 + k] = fmaf(__expf(cB) + 1e-6f, xB[8 + k], bB[k]);
        }
        // register permutation via private LDS slots (uniform runtime indices)
#pragma unroll
        for (int p = 0; p < 16; ++p) { mA[p] = xA[p]; mB[p] = xB[p]; }
        const int* __restrict__ pl = perms + l * 16;
#pragma unroll
        for (int j = 0; j < 16; ++j) { xA[j] = mA[pl[j]]; xB[j] = mB[pl[j]]; }
    }

    {
        float4* ya = reinterpret_cast<float4*>(outy + i * 16);
#pragma unroll
        for (int q = 0; q < 4; ++q) {
            float4 a;
            a.x = xA[4 * q]; a.y = xA[4 * q + 1]; a.z = xA[4 * q + 2]; a.w = xA[4 * q + 3];
            ya[q] = a;
        }
        float4* yb = reinterpret_cast<float4*>(outy + (i + HALF) * 16);
#pragma unroll
        for (int q = 0; q < 4; ++q) {
            float4 a;
            a.x = xB[4 * q]; a.y = xB[4 * q + 1]; a.z = xB[4 * q + 2]; a.w = xB[4 * q + 3];
            yb[q] = a;
        }
    }
    outld[i] = ldA;
    outld[i + HALF] = ldB;
}

extern "C" void kernel_launch(void* const* d_in, const int* in_sizes, int n_in,
                              void* d_out, int out_size, void* d_ws, size_t ws_size,
                              hipStream_t stream) {
    const float* z = (const float*)d_in[0];
    const float* Wi = (const float*)d_in[1];
    const float* bi = (const float*)d_in[2];
    const float* Wh = (const float*)d_in[3];
    const float* bh = (const float*)d_in[4];
    const float* Wo = (const float*)d_in[5];
    const float* bo = (const float*)d_in[6];
    const int* perms = (const int*)d_in[7];
    float* out = (float*)d_out;
    float* slab = (float*)d_ws;   // 151*72 floats

    hipLaunchKernelGGL(build_slab, dim3((NSTG * 72 + 255) / 256), dim3(256), 0, stream,
                       Wi, bi, Wh, bh, Wo, bo, slab);
    hipLaunchKernelGGL(flow_fwd, dim3(HALF / 512), dim3(512), 0, stream,
                       z, slab, perms, out, out + (size_t)BN * 16);
}